// Round 3
// baseline (793.925 us; speedup 1.0000x reference)
//
#include <hip/hip_runtime.h>

// ---------------------------------------------------------------------------
// GQA attention block: QKV proj -> RoPE -> causal GQA flash attention -> out proj
// B=2 S=2048 D=4096 NH=32 NKV=8 HD=128 (QKV_DIM=6144)
// R6: (a) QKV GEMM retiled 128x384 -> 512 blocks = 2 even rounds (R5's 384-
//     block grid wasted half of round 2; busy-CU util was already ~60%).
//     GEMM generalized to template<OUT_BF16,BM,BN>; same verified R5 schedule:
//     2 barriers/tile, stage groups of 4 calls, counted VM4, st_16x32 swizzle.
//     (b) attention: KVBLK 32->64, T14 async-stage (global->reg before
//     compute, reg->LDS after barrier), T13 defer-max (skip rescale when
//     __all(mloc - m <= 8)).
// ---------------------------------------------------------------------------

typedef __bf16 bf16;
typedef bf16 bf16x8 __attribute__((ext_vector_type(8)));
typedef bf16 bf16x4 __attribute__((ext_vector_type(4)));
typedef float f32x4 __attribute__((ext_vector_type(4)));
typedef unsigned int u32;
typedef u32 u32x4 __attribute__((ext_vector_type(4)));

#define B_ 2
#define S_ 2048
#define DM 4096
#define NH 32
#define NKV 8
#define HD 128
#define QKV_DIM 6144

typedef __attribute__((address_space(3))) void lds_void;
typedef const __attribute__((address_space(1))) void glb_void;

__device__ __forceinline__ void gld_lds16(const bf16* g, bf16* l) {
  __builtin_amdgcn_global_load_lds((glb_void*)g, (lds_void*)l, 16, 0, 0);
}

__device__ __forceinline__ u32 bf16bits(float x) {
  union { bf16 h; unsigned short s; } u;
  u.h = (bf16)x;
  return (u32)u.s;
}

#define BAR() __builtin_amdgcn_s_barrier()
#define VM4() asm volatile("s_waitcnt vmcnt(4)" ::: "memory")
#define VM0() asm volatile("s_waitcnt vmcnt(0)" ::: "memory")
#define PRIO1() __builtin_amdgcn_s_setprio(1)
#define PRIO0() __builtin_amdgcn_s_setprio(0)

// ---------------- cast fp32 -> bf16 (hidden states) ----------------
__global__ __launch_bounds__(256) void cast_f32_bf16(const float* __restrict__ src,
                                                     bf16* __restrict__ dst, int n) {
  int i = (blockIdx.x * 256 + threadIdx.x) * 4;
  float4 v = *(const float4*)(src + i);
  bf16x4 o;
  o[0] = (bf16)v.x; o[1] = (bf16)v.y; o[2] = (bf16)v.z; o[3] = (bf16)v.w;
  *(bf16x4*)(dst + i) = o;
}

// ---------------- transpose + cast weights: W[K][N] f32 -> Wt[N][K] bf16 ----
__global__ __launch_bounds__(256) void transpose_cast_w(const float* __restrict__ W,
                                                        bf16* __restrict__ Wt,
                                                        int K, int N) {
  __shared__ float tile[64][65];
  const int n0 = blockIdx.x * 64, k0 = blockIdx.y * 64;
  const int t = threadIdx.x, j = t & 63, i0 = t >> 6;
  for (int p = 0; p < 16; ++p) {
    int i = i0 + p * 4;
    tile[i][j] = W[(size_t)(k0 + i) * N + n0 + j];
  }
  __syncthreads();
  for (int p = 0; p < 16; ++p) {
    int n = i0 + p * 4;
    Wt[(size_t)(n0 + n) * K + k0 + j] = (bf16)tile[j][n];
  }
}

// ---------------- transpose V out of qkv: v_t[b][kv][d][s] ----------------
__global__ __launch_bounds__(256) void transpose_v(const bf16* __restrict__ qkv,
                                                   bf16* __restrict__ v_t) {
  __shared__ bf16 tile[64][65];
  const int s0 = blockIdx.x * 64;
  const int d0 = blockIdx.y * 64;
  const int bk = blockIdx.z;            // b*8+kv
  const int b = bk >> 3, kv = bk & 7;
  const int t = threadIdx.x, j = t & 63, i0 = t >> 6;
  const bf16* src = qkv + (size_t)b * S_ * QKV_DIM + 5120 + kv * HD;  // v offset 5120
  for (int p = 0; p < 16; ++p) {
    int i = i0 + p * 4;
    tile[i][j] = src[(size_t)(s0 + i) * QKV_DIM + d0 + j];
  }
  __syncthreads();
  bf16* dst = v_t + ((size_t)bk * HD + d0) * S_ + s0;
  for (int p = 0; p < 16; ++p) {
    int dd = i0 + p * 4;
    dst[(size_t)dd * S_ + j] = tile[j][dd];
  }
}

// ---------------- RoPE + repack q,k (q pre-scaled by 1/sqrt(HD)) ----------
__global__ __launch_bounds__(128) void rope_kernel(const bf16* __restrict__ qkv,
                                                   const float* __restrict__ cosT,
                                                   const float* __restrict__ sinT,
                                                   bf16* __restrict__ q_r,
                                                   bf16* __restrict__ k_r) {
  const int bs = blockIdx.x;            // b*S + s
  const int b = bs >> 11, s = bs & 2047;
  const int d = threadIdx.x;            // 0..127
  const float cv = cosT[s * HD + d];
  const float sv = sinT[s * HD + d];
  const bf16* row = qkv + (size_t)bs * QKV_DIM;
  const float scale = 0.08838834764831845f;  // 1/sqrt(128)
  for (int h = 0; h < NH; ++h) {
    float x = (float)row[h * HD + d];
    float xr = (d < 64) ? -(float)row[h * HD + d + 64] : (float)row[h * HD + d - 64];
    q_r[(((size_t)(b * NH + h)) * S_ + s) * HD + d] = (bf16)((x * cv + xr * sv) * scale);
  }
  for (int kv = 0; kv < NKV; ++kv) {
    float x = (float)row[DM + kv * HD + d];
    float xr = (d < 64) ? -(float)row[DM + kv * HD + d + 64] : (float)row[DM + kv * HD + d - 64];
    k_r[(((size_t)(b * NKV + kv)) * S_ + s) * HD + d] = (bf16)(x * cv + xr * sv);
  }
}

// ---------------- GEMM: C[M][N] = A[M][K] * Bt[N][K]^T  (BM x BN tiles) -----
// 512 threads = 8 waves (2 Mrows x 4 Ncols), per-wave output (BM/2)x(BN/4).
// BK=64 as two K-halves; per buffer: A[2kh][BM][32] + B[2kh][BN][32] bf16 =
// 64 KiB; double-buffered = 128 KiB. Stage group (one kh of A+B) is always
// (BM+BN)/128 = 4 global_load_lds calls/wave -> VM4 counting identical for
// both tilings. Schedule = R5's verified skeleton: BAR; read kh0 frags;
// stage t+1-kh1 -> P^1; MFMA kh0; read kh1 frags; BAR; stage t+2-kh0 -> P;
// MFMA kh1; VM4 (retires all of t+1's calls, leaves t+2-kh0 in flight).
template <bool OUT_BF16, int BM, int BN>
__global__ __launch_bounds__(512, 2) void gemm_bt(const bf16* __restrict__ A,
                                                  const bf16* __restrict__ Bt,
                                                  void* __restrict__ Cout,
                                                  int M, int N, int K) {
  constexpr int MF = BM / 32;           // m-frags per wave
  constexpr int NF = BN / 64;           // n-frags per wave
  constexpr int NCA = BM / 128;         // A stage calls per kh per wave
  constexpr int NCB = BN / 128;         // B stage calls per kh per wave
  constexpr int AKH = BM * 64;          // bytes per A kh region
  constexpr int BKH = BN * 64;          // bytes per B kh region
  constexpr int BUF = 2 * (AKH + BKH);  // 65536 for both tilings
  extern __shared__ char lds[];
  const int NT = K >> 6;                // K-tiles of 64 (K=4096 -> 64, even)

  // bijective XCD swizzle (grids are multiples of 8)
  const int nwg = gridDim.x;
  const int cpx = nwg >> 3;
  const int wg = (blockIdx.x & 7) * cpx + (blockIdx.x >> 3);
  const int nbx = N / BN;
  const int bx = wg % nbx, by = wg / nbx;
  const int m0 = by * BM, n0 = bx * BN;

  const int t = threadIdx.x;
  const int w = t >> 6, lane = t & 63;
  const int wr = w >> 2, wc = w & 3;    // wave grid 2 x 4
  const int quad = lane >> 4, c = lane & 15;

  // swizzled ds_read base offsets (byte bit5 ^= row&8; all added bases are
  // multiples of 1024 so the XOR commutes). Verified R4/R5: 0 bank conflicts.
  const int aOff = (((wr * (BM / 2) + c) * 64 + quad * 16) ^ ((c & 8) << 2));
  const int bOff = 2 * AKH + ((((wc * (BN / 4) + c) * 64 + quad * 16) ^ ((c & 8) << 2)));

  // staging: per kh, wave w covers A rows [w*BM/8, +BM/8) and B rows
  // [w*BN/8, +BN/8) in 16-row calls; global col-granule pre-swizzled so the
  // linear global_load_lds dest lands swizzled data.
  const int scol = (((lane & 3) ^ ((lane >> 4) & 2)) << 3);  // elements
  const bf16* gA[NCA];
  const bf16* gB[NCB];
#pragma unroll
  for (int cc = 0; cc < NCA; ++cc)
    gA[cc] = A + (size_t)(m0 + w * (BM / 8) + cc * 16 + (lane >> 2)) * K + scol;
#pragma unroll
  for (int cc = 0; cc < NCB; ++cc)
    gB[cc] = Bt + (size_t)(n0 + w * (BN / 8) + cc * 16 + (lane >> 2)) * K + scol;

  auto stageKh = [&](int P, int kh, int ke) {
    char* ab = lds + P * BUF + kh * AKH + w * (BM * 8);
#pragma unroll
    for (int cc = 0; cc < NCA; ++cc) gld_lds16(gA[cc] + ke, (bf16*)(ab + cc * 1024));
    char* bb = lds + P * BUF + 2 * AKH + kh * BKH + w * (BN * 8);
#pragma unroll
    for (int cc = 0; cc < NCB; ++cc) gld_lds16(gB[cc] + ke, (bf16*)(bb + cc * 1024));
  };

  bf16x8 a0[MF], b0v[NF], a1[MF], b1v[NF];
  auto ldFr = [&](int P, int kh, bf16x8* av, bf16x8* bv) {
    const char* ab = lds + P * BUF + kh * AKH + aOff;
#pragma unroll
    for (int i = 0; i < MF; ++i) av[i] = *(const bf16x8*)(ab + i * 1024);
    const char* bb = lds + P * BUF + kh * BKH + bOff;  // bOff includes 2*AKH
#pragma unroll
    for (int j = 0; j < NF; ++j) bv[j] = *(const bf16x8*)(bb + j * 1024);
  };

  f32x4 acc[MF][NF];
#pragma unroll
  for (int i = 0; i < MF; ++i)
#pragma unroll
    for (int j = 0; j < NF; ++j) acc[i][j] = (f32x4){0.f, 0.f, 0.f, 0.f};

  auto mfmac = [&](bf16x8* av, bf16x8* bv) {
    PRIO1();
#pragma unroll
    for (int i = 0; i < MF; ++i)
#pragma unroll
      for (int j = 0; j < NF; ++j)
        acc[i][j] = __builtin_amdgcn_mfma_f32_16x16x32_bf16(av[i], bv[j], acc[i][j], 0, 0, 0);
    PRIO0();
  };

  auto gtile = [&](int P, bool S0, bool S1) {
    BAR();
    ldFr(P, 0, a0, b0v);
    if (S0) stageKh(P ^ 1, 1, 96);      // t+1's kh1 -> other buffer
    mfmac(a0, b0v);
    ldFr(P, 1, a1, b1v);
    BAR();
    if (S1) stageKh(P, 0, 128);         // t+2's kh0 -> this buffer
    mfmac(a1, b1v);
  };

  auto adv = [&]() {
#pragma unroll
    for (int cc = 0; cc < NCA; ++cc) gA[cc] += 64;
#pragma unroll
    for (int cc = 0; cc < NCB; ++cc) gB[cc] += 64;
  };

  // prologue: tile0 both kh + tile1 kh0; retire tile0's groups (VM4 leaves
  // tile1-kh0's 4 calls in flight)
  stageKh(0, 0, 0); stageKh(0, 1, 32); stageKh(1, 0, 64);
  VM4();

  for (int tt = 0; tt < NT - 2; tt += 2) {
    gtile(0, true, true); VM4(); adv();
    gtile(1, true, true); VM4(); adv();
  }
  gtile(0, true, false); VM0();         // penultimate: stage NT-1's kh1 only
  gtile(1, false, false);               // last: no staging

  // epilogue: C write (verified fragment mapping: row=quad*4+r, col=c)
  const int crow = m0 + wr * (BM / 2) + quad * 4;
  const int ccol = n0 + wc * (BN / 4) + c;
#pragma unroll
  for (int mf = 0; mf < MF; ++mf)
#pragma unroll
    for (int nn = 0; nn < NF; ++nn) {
      const int row = crow + mf * 16;
      const int col = ccol + nn * 16;
      if constexpr (OUT_BF16) {
        bf16* Cp = (bf16*)Cout;
#pragma unroll
        for (int r = 0; r < 4; ++r) Cp[(size_t)(row + r) * N + col] = (bf16)acc[mf][nn][r];
      } else {
        float* Cp = (float*)Cout;
#pragma unroll
        for (int r = 0; r < 4; ++r) Cp[(size_t)(row + r) * N + col] = acc[mf][nn][r];
      }
    }
}

// ---------------- flash attention (causal GQA, transposed-S) ---------------
// grid: (B*NH, S/64). 4 waves/block, wave w owns q rows [q0+16w, q0+16w+16).
// R6: K-chunk = 64 keys (4 key-tiles), T14 async staging (global->reg issued
// before compute, reg->LDS after barrier), T13 defer-max (THR=8).
// S^T = K*Q^T: lane (c,quad) holds 16 scores (4 tiles x 4 regs) for its one
// q-row -> softmax in-register + 2 shfl. P->A-layout via 16 shuffles (2 PV
// K-groups of 32 keys each).
#define KVB 64
#define SKS 136
#define SVS 72
__global__ __launch_bounds__(256) void attn_kernel(const bf16* __restrict__ q_r,
                                                   const bf16* __restrict__ k_r,
                                                   const bf16* __restrict__ v_t,
                                                   bf16* __restrict__ attn_out) {
  __shared__ bf16 Ks[KVB * SKS];   // [key][d]  64 x (128+8)
  __shared__ bf16 Vs[128 * SVS];   // [d][key] 128 x (64+8)

  const int bh = blockIdx.x;           // b*NH + h
  const int b = bh >> 5, h = bh & 31;
  const int kv = h >> 2;               // N_GROUPS = 4
  const int q0 = blockIdx.y * 64;
  const int t = threadIdx.x, w = t >> 6, lane = t & 63;
  const int quad = lane >> 4, c = lane & 15;
  const int myq = q0 + w * 16 + c;     // the q row this lane owns for softmax

  // Q B-frags (B[n=q][k=d]), held in registers across the whole K loop
  const bf16* qrow = q_r + ((size_t)(b * NH + h) * S_ + myq) * HD;
  bf16x8 qf[4];
#pragma unroll
  for (int kk = 0; kk < 4; ++kk) qf[kk] = *(const bf16x8*)(qrow + quad * 8 + kk * 32);

  float m_i = -1e30f, l_i = 0.f;       // per-lane (row = myq)
  f32x4 o_acc[8];
#pragma unroll
  for (int n = 0; n < 8; ++n) o_acc[n] = (f32x4){0.f, 0.f, 0.f, 0.f};

  const bf16* kb_ptr = k_r + (size_t)(b * NKV + kv) * S_ * HD;
  const bf16* vb_ptr = v_t + (size_t)(b * NKV + kv) * HD * S_;

  const int nch = blockIdx.y + 1;      // chunks of 64 keys (covers q0+64 keys)

  // staging: thread t loads 64B of K (key t>>2, d (t&3)*32..) and 64B of V
  // (d t>>1, keys (t&1)*32..)
  const int kkey = t >> 2, kdoff = (t & 3) * 32;
  const int vd = t >> 1, vkoff = (t & 1) * 32;
  const bf16* kp = kb_ptr + (size_t)kkey * HD + kdoff;
  const bf16* vp = vb_ptr + (size_t)vd * S_ + vkoff;

  // P-conversion shuffle sources (per 32-key group): lane (c,quad) pulls key
  // 8q+j from lane c+32*(quad&1) (j<4) / +16 (j>=4); tile select = quad>>1.
  const int src0 = c + 32 * (quad & 1);
  const int src1 = src0 + 16;
  const bool hiTile = (quad & 2) != 0;

  auto packP = [&](const float* ea, const float* eb) -> bf16x8 {
    u32 pk[4];
#pragma unroll
    for (int r = 0; r < 4; ++r) pk[r] = bf16bits(ea[r]) | (bf16bits(eb[r]) << 16);
    u32 a0[4], a1[4];
#pragma unroll
    for (int r = 0; r < 4; ++r) {
      a0[r] = (u32)__shfl((int)pk[r], src0, 64);
      a1[r] = (u32)__shfl((int)pk[r], src1, 64);
    }
    u32 w0, w1, w2, w3;
    if (hiTile) {
      w0 = (a0[0] >> 16) | (a0[1] & 0xffff0000u);
      w1 = (a0[2] >> 16) | (a0[3] & 0xffff0000u);
      w2 = (a1[0] >> 16) | (a1[1] & 0xffff0000u);
      w3 = (a1[2] >> 16) | (a1[3] & 0xffff0000u);
    } else {
      w0 = (a0[0] & 0xffffu) | (a0[1] << 16);
      w1 = (a0[2] & 0xffffu) | (a0[3] << 16);
      w2 = (a1[0] & 0xffffu) | (a1[1] << 16);
      w3 = (a1[2] & 0xffffu) | (a1[3] << 16);
    }
    return __builtin_bit_cast(bf16x8, (u32x4){w0, w1, w2, w3});
  };

  // T14 prologue: chunk 0 -> regs
  bf16x8 krg[4], vrg[4];
#pragma unroll
  for (int i = 0; i < 4; ++i) {
    krg[i] = *(const bf16x8*)(kp + i * 8);
    vrg[i] = *(const bf16x8*)(vp + i * 8);
  }

  for (int ch = 0; ch < nch; ++ch) {
    const int kb = ch * KVB;
    __syncthreads();   // previous chunk's LDS reads done before overwrite
#pragma unroll
    for (int i = 0; i < 4; ++i) {
      *(bf16x8*)(Ks + kkey * SKS + kdoff + i * 8) = krg[i];
      *(bf16x8*)(Vs + vd * SVS + vkoff + i * 8) = vrg[i];
    }
    if (ch + 1 < nch) {                // issue next chunk's loads (T14)
      kp += (size_t)KVB * HD;
      vp += KVB;
#pragma unroll
      for (int i = 0; i < 4; ++i) {
        krg[i] = *(const bf16x8*)(kp + i * 8);
        vrg[i] = *(const bf16x8*)(vp + i * 8);
      }
    }
    __syncthreads();

    if (kb <= q0 + w * 16 + 15) {      // wave has at least one unmasked key
      // S^T = K Q^T : four 16(key)x16(q) tiles
      f32x4 st0 = (f32x4){0.f, 0.f, 0.f, 0.f};
      f32x4 st1 = (f32x4){0.f, 0.f, 0.f, 0.f};
      f32x4 st2 = (f32x4){0.f, 0.f, 0.f, 0.f};
      f32x4 st3 = (f32x4){0.f, 0.f, 0.f, 0.f};
#pragma unroll
      for (int kk = 0; kk < 4; ++kk) {
        bf16x8 kf0 = *(const bf16x8*)(Ks + (c) * SKS + quad * 8 + kk * 32);
        bf16x8 kf1 = *(const bf16x8*)(Ks + (16 + c) * SKS + quad * 8 + kk * 32);
        bf16x8 kf2 = *(const bf16x8*)(Ks + (32 + c) * SKS + quad * 8 + kk * 32);
        bf16x8 kf3 = *(const bf16x8*)(Ks + (48 + c) * SKS + quad * 8 + kk * 32);
        st0 = __builtin_amdgcn_mfma_f32_16x16x32_bf16(kf0, qf[kk], st0, 0, 0, 0);
        st1 = __builtin_amdgcn_mfma_f32_16x16x32_bf16(kf1, qf[kk], st1, 0, 0, 0);
        st2 = __builtin_amdgcn_mfma_f32_16x16x32_bf16(kf2, qf[kk], st2, 0, 0, 0);
        st3 = __builtin_amdgcn_mfma_f32_16x16x32_bf16(kf3, qf[kk], st3, 0, 0, 0);
      }

      // masking (key of st{kt} reg r = kb + kt*16 + quad*4 + r, row = myq)
      float e0[4], e1[4], e2[4], e3[4];
#pragma unroll
      for (int r = 0; r < 4; ++r) { e0[r] = st0[r]; e1[r] = st1[r]; e2[r] = st2[r]; e3[r] = st3[r]; }
      if (kb + 63 > q0 + w * 16) {
        const int key0 = kb + quad * 4;
#pragma unroll
        for (int r = 0; r < 4; ++r) {
          if (key0 + r > myq) e0[r] = -1e30f;
          if (key0 + 16 + r > myq) e1[r] = -1e30f;
          if (key0 + 32 + r > myq) e2[r] = -1e30f;
          if (key0 + 48 + r > myq) e3[r] = -1e30f;
        }
      }

      // softmax for row myq: in-reg over 16 vals + 2 shfl across quads
      float mloc = fmaxf(fmaxf(fmaxf(e0[0], e0[1]), fmaxf(e0[2], e0[3])),
                         fmaxf(fmaxf(e1[0], e1[1]), fmaxf(e1[2], e1[3])));
      mloc = fmaxf(mloc, fmaxf(fmaxf(fmaxf(e2[0], e2[1]), fmaxf(e2[2], e2[3])),
                               fmaxf(fmaxf(e3[0], e3[1]), fmaxf(e3[2], e3[3]))));
      mloc = fmaxf(mloc, __shfl_xor(mloc, 16, 64));
      mloc = fmaxf(mloc, __shfl_xor(mloc, 32, 64));
      const bool defer = (__all(mloc - m_i <= 8.0f) != 0);  // T13, THR=8
      const float mnew = defer ? m_i : fmaxf(m_i, mloc);
      float sum = 0.f;
#pragma unroll
      for (int r = 0; r < 4; ++r) {
        e0[r] = __expf(e0[r] - mnew); sum += e0[r];
        e1[r] = __expf(e1[r] - mnew); sum += e1[r];
        e2[r] = __expf(e2[r] - mnew); sum += e2[r];
        e3[r] = __expf(e3[r] - mnew); sum += e3[r];
      }
      sum += __shfl_xor(sum, 16, 64);
      sum += __shfl_xor(sum, 32, 64);
      if (!defer) {
        const float alpha = __expf(m_i - mnew);
        m_i = mnew;
        l_i = l_i * alpha + sum;
        float alpha_o[4];
#pragma unroll
        for (int r = 0; r < 4; ++r) alpha_o[r] = __shfl(alpha, quad * 4 + r, 64);
#pragma unroll
        for (int n = 0; n < 8; ++n)
#pragma unroll
          for (int r = 0; r < 4; ++r) o_acc[n][r] *= alpha_o[r];
      } else {
        l_i += sum;
      }

      // P -> MFMA A-layout, two 32-key groups
      bf16x8 pf0 = packP(e0, e1);
      bf16x8 pf1 = packP(e2, e3);

      // O += P V
#pragma unroll
      for (int n = 0; n < 8; ++n) {
        bf16x8 vf0 = *(const bf16x8*)(Vs + (n * 16 + c) * SVS + quad * 8);
        o_acc[n] = __builtin_amdgcn_mfma_f32_16x16x32_bf16(pf0, vf0, o_acc[n], 0, 0, 0);
        bf16x8 vf1 = *(const bf16x8*)(Vs + (n * 16 + c) * SVS + 32 + quad * 8);
        o_acc[n] = __builtin_amdgcn_mfma_f32_16x16x32_bf16(pf1, vf1, o_acc[n], 0, 0, 0);
      }
    }
  }

  // epilogue: O /= l (l for row quad*4+r lives at lane quad*4+r), write out
  float l_o[4];
#pragma unroll
  for (int r = 0; r < 4; ++r) l_o[r] = __shfl(l_i, quad * 4 + r, 64);
#pragma unroll
  for (int n = 0; n < 8; ++n)
#pragma unroll
    for (int r = 0; r < 4; ++r) {
      const int row = q0 + w * 16 + quad * 4 + r;
      const float ov = o_acc[n][r] / l_o[r];
      attn_out[((size_t)b * S_ + row) * DM + h * HD + n * 16 + c] = (bf16)ov;
    }
}

// ---------------------------------------------------------------------------
extern "C" void kernel_launch(void* const* d_in, const int* in_sizes, int n_in,
                              void* d_out, int out_size, void* d_ws, size_t ws_size,
                              hipStream_t stream) {
  const float* hidden = (const float*)d_in[0];
  const float* cosT = (const float*)d_in[1];
  const float* sinT = (const float*)d_in[2];
  const float* Wqkv = (const float*)d_in[3];
  const float* Wout = (const float*)d_in[4];
  float* out = (float*)d_out;
  char* ws = (char*)d_ws;

  bf16* WqkvT = (bf16*)(ws + 0);
  bf16* q_r = (bf16*)(ws + 0);
  bf16* k_r = (bf16*)(ws + 33554432);
  bf16* WoutT = (bf16*)(ws + 50331648);
  bf16* h_bf = (bf16*)(ws + 83886080);
  bf16* attn_out = (bf16*)(ws + 83886080);
  bf16* v_t = (bf16*)(ws + 117440512);
  bf16* qkv = (bf16*)d_out;

  static bool attr_set = false;
  if (!attr_set) {
    hipFuncSetAttribute(reinterpret_cast<const void*>(&gemm_bt<true, 128, 384>),
                        hipFuncAttributeMaxDynamicSharedMemorySize, 131072);
    hipFuncSetAttribute(reinterpret_cast<const void*>(&gemm_bt<false, 256, 256>),
                        hipFuncAttributeMaxDynamicSharedMemorySize, 131072);
    attr_set = true;
  }

  cast_f32_bf16<<<dim3(16384), dim3(256), 0, stream>>>(hidden, h_bf, B_ * S_ * DM);
  transpose_cast_w<<<dim3(QKV_DIM / 64, DM / 64), dim3(256), 0, stream>>>(Wqkv, WqkvT, DM, QKV_DIM);
  transpose_cast_w<<<dim3(DM / 64, DM / 64), dim3(256), 0, stream>>>(Wout, WoutT, DM, DM);
  gemm_bt<true, 128, 384><<<dim3((QKV_DIM / 384) * ((B_ * S_) / 128)), dim3(512), 131072, stream>>>(
      h_bf, WqkvT, (void*)qkv, B_ * S_, QKV_DIM, DM);
  rope_kernel<<<dim3(B_ * S_), dim3(128), 0, stream>>>(qkv, cosT, sinT, q_r, k_r);
  transpose_v<<<dim3(S_ / 64, HD / 64, B_ * NKV), dim3(256), 0, stream>>>(qkv, v_t);
  attn_kernel<<<dim3(B_ * NH, S_ / 64), dim3(256), 0, stream>>>(q_r, k_r, v_t, attn_out);
  gemm_bt<false, 256, 256><<<dim3((DM / 256) * ((B_ * S_) / 256)), dim3(512), 131072, stream>>>(
      attn_out, WoutT, (void*)out, B_ * S_, DM, DM);
}